// Round 1
// baseline (267.068 us; speedup 1.0000x reference)
//
#include <hip/hip_runtime.h>
#include <math.h>

#define D_MODEL 2048
#define NUM_EXP 64

// ---------------------------------------------------------------------------
// Kernel 1: split-K partial GEMM. logits_partial[kb][token][expert] (fp32).
// Block: 256 threads = 4 waves. Tile: 256 tokens x 64 experts.
// Thread fragment: 8 tokens x 8 experts (64 fp32 accumulators).
// Lane layout: tx = lane%8 (expert group), ty = lane/8 (token group) ->
//   x-load addr depends only on ty (8 unique/wave, 8-lane broadcast),
//   W-load addr depends only on tx (8 unique/wave, 8-lane broadcast).
// No LDS, no syncthreads: pure register tiling, x read exactly once from HBM.
// ---------------------------------------------------------------------------
template<int KC>
__global__ __launch_bounds__(256, 2)
void k1_partial_gemm(const float* __restrict__ x, const float* __restrict__ W,
                     float* __restrict__ partial, int N) {
    const int tid  = threadIdx.x;
    const int tx   = tid & 7;         // expert group: experts tx*8 .. tx*8+7
    const int ty   = tid >> 3;        // token group: 0..31
    const int tile = blockIdx.x;      // 256-token tile
    const int kb   = blockIdx.y;      // k-slice
    const int tok0  = tile * 256 + ty * 8;
    const int kbase = kb * KC;

    const float4* xr[8];
    const float4* wr[8];
#pragma unroll
    for (int i = 0; i < 8; ++i)
        xr[i] = reinterpret_cast<const float4*>(x + (size_t)(tok0 + i) * D_MODEL + kbase);
#pragma unroll
    for (int j = 0; j < 8; ++j)
        wr[j] = reinterpret_cast<const float4*>(W + (size_t)(tx * 8 + j) * D_MODEL + kbase);

    float acc[8][8];
#pragma unroll
    for (int i = 0; i < 8; ++i)
#pragma unroll
        for (int j = 0; j < 8; ++j) acc[i][j] = 0.f;

#pragma unroll 2
    for (int kc = 0; kc < KC / 4; ++kc) {
        float4 a[8], b[8];
#pragma unroll
        for (int i = 0; i < 8; ++i) a[i] = xr[i][kc];
#pragma unroll
        for (int j = 0; j < 8; ++j) b[j] = wr[j][kc];
#pragma unroll
        for (int i = 0; i < 8; ++i) {
#pragma unroll
            for (int j = 0; j < 8; ++j) {
                acc[i][j] += a[i].x * b[j].x;
                acc[i][j] += a[i].y * b[j].y;
                acc[i][j] += a[i].z * b[j].z;
                acc[i][j] += a[i].w * b[j].w;
            }
        }
    }

    // partial[kb][token][expert]
    float* base = partial + ((size_t)kb * N + tok0) * NUM_EXP + tx * 8;
#pragma unroll
    for (int i = 0; i < 8; ++i) {
        float4 lo = make_float4(acc[i][0], acc[i][1], acc[i][2], acc[i][3]);
        float4 hi = make_float4(acc[i][4], acc[i][5], acc[i][6], acc[i][7]);
        float4* p = reinterpret_cast<float4*>(base + (size_t)i * NUM_EXP);
        p[0] = lo;
        p[1] = hi;
    }
}

// ---------------------------------------------------------------------------
// Kernel 2: one wave per token (lane == expert). Sum partials in fixed ks
// order (deterministic), softmax across the wave, top-2 with lax.top_k tie
// rule (lower index wins), write weights + indices (as float), accumulate
// per-block expert prob sums / selection counts into ws (no atomics).
// ---------------------------------------------------------------------------
__global__ __launch_bounds__(256)
void k2_finalize(const float* __restrict__ partial, float* __restrict__ out,
                 float* __restrict__ p_part, float* __restrict__ f_part,
                 int N, int KS) {
    const int lane = threadIdx.x & 63;
    const int wid  = threadIdx.x >> 6;          // 0..3
    const int gw   = blockIdx.x * 4 + wid;      // global wave id
    const int NW   = gridDim.x * 4;

    float pacc = 0.f, facc = 0.f;

    for (int t = gw; t < N; t += NW) {
        float logit = 0.f;
        for (int ks = 0; ks < KS; ++ks)
            logit += partial[((size_t)ks * N + t) * NUM_EXP + lane];

        // wave max (for softmax stability)
        float m = logit;
        for (int off = 32; off; off >>= 1) m = fmaxf(m, __shfl_xor(m, off));
        float p = __expf(logit - m);
        float S = p;
        for (int off = 32; off; off >>= 1) S += __shfl_xor(S, off);
        float prob = p / S;

        // top-1 (argmax, ties -> lower index)
        float bv = logit; int bi = lane;
        for (int off = 32; off; off >>= 1) {
            float ov = __shfl_xor(bv, off);
            int   oi = __shfl_xor(bi, off);
            if (ov > bv || (ov == bv && oi < bi)) { bv = ov; bi = oi; }
        }
        // top-2: mask winner, argmax again
        float cv = (lane == bi) ? -INFINITY : logit;
        int   ci = lane;
        for (int off = 32; off; off >>= 1) {
            float ov = __shfl_xor(cv, off);
            int   oi = __shfl_xor(ci, off);
            if (ov > cv || (ov == cv && oi < ci)) { cv = ov; ci = oi; }
        }

        if (lane == 0) {
            // topk_probs / sum(topk_probs) == 1/(1+exp(l2-l1))
            float w0 = 1.f / (1.f + __expf(cv - bv));
            out[(size_t)t * 2]     = w0;
            out[(size_t)t * 2 + 1] = 1.f - w0;
            out[(size_t)2 * N + t * 2]     = (float)bi;
            out[(size_t)2 * N + t * 2 + 1] = (float)ci;
        }

        pacc += prob;
        facc += (lane == bi ? 1.f : 0.f) + (lane == ci ? 1.f : 0.f);
    }

    __shared__ float lp[4][64];
    __shared__ float lf[4][64];
    lp[wid][lane] = pacc;
    lf[wid][lane] = facc;
    __syncthreads();
    if (wid == 0) {
        float sp = lp[0][lane] + lp[1][lane] + lp[2][lane] + lp[3][lane];
        float sf = lf[0][lane] + lf[1][lane] + lf[2][lane] + lf[3][lane];
        p_part[(size_t)blockIdx.x * NUM_EXP + lane] = sp;
        f_part[(size_t)blockIdx.x * NUM_EXP + lane] = sf;
    }
}

// ---------------------------------------------------------------------------
// Kernel 3: deterministic aux-loss reduction over per-block partials.
// aux = E * sum_i (f_sum_i / N) * (p_sum_i / N)
// ---------------------------------------------------------------------------
__global__ void k3_aux(const float* __restrict__ p_part, const float* __restrict__ f_part,
                       float* __restrict__ out, int N, int B2) {
    const int lane = threadIdx.x;   // 64 threads
    float sp = 0.f, sf = 0.f;
    for (int b = 0; b < B2; ++b) {
        sp += p_part[(size_t)b * NUM_EXP + lane];
        sf += f_part[(size_t)b * NUM_EXP + lane];
    }
    float v = sp * sf;
    for (int off = 32; off; off >>= 1) v += __shfl_xor(v, off);
    if (lane == 0)
        out[(size_t)4 * N] = (float)NUM_EXP * v / ((float)N * (float)N);
}

extern "C" void kernel_launch(void* const* d_in, const int* in_sizes, int n_in,
                              void* d_out, int out_size, void* d_ws, size_t ws_size,
                              hipStream_t stream) {
    const float* x = (const float*)d_in[0];
    const float* W = (const float*)d_in[1];
    float* out = (float*)d_out;

    const int N = in_sizes[0] / D_MODEL;   // 16384

    const int B2 = 256;                    // kernel-2 block count
    const size_t acc_bytes = (size_t)B2 * NUM_EXP * sizeof(float) * 2;

    // choose split-K factor by available workspace (deterministic per run)
    int KS = 1;
    if      ((size_t)8 * N * NUM_EXP * 4 + acc_bytes <= ws_size) KS = 8;
    else if ((size_t)4 * N * NUM_EXP * 4 + acc_bytes <= ws_size) KS = 4;
    else if ((size_t)2 * N * NUM_EXP * 4 + acc_bytes <= ws_size) KS = 2;

    float* partial = (float*)d_ws;
    float* p_part  = partial + (size_t)KS * N * NUM_EXP;
    float* f_part  = p_part + (size_t)B2 * NUM_EXP;

    dim3 g1(N / 256, KS), b1(256);
    switch (KS) {
        case 8:  k1_partial_gemm<256 ><<<g1, b1, 0, stream>>>(x, W, partial, N); break;
        case 4:  k1_partial_gemm<512 ><<<g1, b1, 0, stream>>>(x, W, partial, N); break;
        case 2:  k1_partial_gemm<1024><<<g1, b1, 0, stream>>>(x, W, partial, N); break;
        default: k1_partial_gemm<2048><<<g1, b1, 0, stream>>>(x, W, partial, N); break;
    }
    k2_finalize<<<B2, 256, 0, stream>>>(partial, out, p_part, f_part, N, KS);
    k3_aux<<<1, 64, 0, stream>>>(p_part, f_part, out, N, B2);
}